// Round 1
// baseline (2308.991 us; speedup 1.0000x reference)
//
#include <hip/hip_runtime.h>
#include <math.h>

// Problem constants
#define BB   64
#define CC   1024
#define HWC  144          // 12*12 cropped
#define KK   8192         // embeddings
#define MM   9216         // BB*HWC pixels

// ws layout (in floats)
#define OFF_FT   0                        // 9216*1024
#define OFF_FSQ  (MM*CC)                  // 9216
#define OFF_ESQ  (OFF_FSQ + MM)           // 8192
#define OFF_PMAX (OFF_ESQ + KK)           // 64*8*144
#define OFF_RMAX (OFF_PMAX + BB*8*HWC)    // 9216
#define OFF_PSUM (OFF_RMAX + MM)          // 64*8*144
#define OFF_RINV (OFF_PSUM + BB*8*HWC)    // 9216
#define WS_FLOATS (OFF_RINV + MM)

// ---------------------------------------------------------------------------
// 1) Crop features[:, :, 1:-1, 1:-1] and transpose to fT[p][c] (p = b*144+hw)
//    LDS-tiled so both global read and global write are coalesced.
__global__ void crop_transpose(const float* __restrict__ feat,
                               float* __restrict__ fT) {
    __shared__ float tile[64][145];   // [c-sub][hw], pad 145 -> stride 17 mod 32
    int cb = blockIdx.x;              // 16 c-blocks of 64
    int b  = blockIdx.y;
    for (int idx = threadIdx.x; idx < 64 * 144; idx += 256) {
        int r  = idx / 144;
        int hw = idx - r * 144;
        int h  = hw / 12, w = hw - h * 12;
        tile[r][hw] = feat[(size_t)((b * 1024 + cb * 64 + r) * 196)
                           + (h + 1) * 14 + (w + 1)];
    }
    __syncthreads();
    for (int idx = threadIdx.x; idx < 64 * 144; idx += 256) {
        int hw = idx >> 6;
        int c0 = idx & 63;
        fT[(size_t)(b * 144 + hw) * 1024 + cb * 64 + c0] = tile[c0][hw];
    }
}

// ---------------------------------------------------------------------------
// 2) Row sum-of-squares (used for both fT rows and embedding rows). C=1024.
__global__ void rowsumsq(const float* __restrict__ src,
                         float* __restrict__ dst) {
    int row = blockIdx.x * 4 + (threadIdx.x >> 6);
    int l   = threadIdx.x & 63;
    const float4* p = reinterpret_cast<const float4*>(src + (size_t)row * 1024);
    float s = 0.f;
#pragma unroll
    for (int it = 0; it < 4; ++it) {
        float4 v = p[l + it * 64];
        s += v.x * v.x + v.y * v.y + v.z * v.z + v.w * v.w;
    }
#pragma unroll
    for (int off = 32; off; off >>= 1) s += __shfl_down(s, off);
    if (l == 0) dst[row] = s;
}

// ---------------------------------------------------------------------------
// 3) f32 GEMM: logits[b][k][hw] = inv * (2*dot(f_p, e_k) - fsq[p] - esq[k])
//    Tiles: BM=BN=128, BK=8, 256 threads, 8x8 per thread (4+4 split rows/cols)
__global__ __launch_bounds__(256)
void gemm_logits(const float* __restrict__ fT, const float* __restrict__ emb,
                 const float* __restrict__ fsq, const float* __restrict__ esq,
                 const float* __restrict__ mdm, float* __restrict__ codes) {
    __shared__ float As[8][128];
    __shared__ float Bs[8][128];
    int bn = blockIdx.x, bm = blockIdx.y;
    int tid = threadIdx.x;
    int tx = tid & 15, ty = tid >> 4;
    int row = tid >> 1, half = tid & 1;

    const float* aptr = fT  + (size_t)(bm * 128 + row) * 1024 + half * 4;
    const float* bptr = emb + (size_t)(bn * 128 + row) * 1024 + half * 4;

    float acc[8][8];
#pragma unroll
    for (int i = 0; i < 8; ++i)
#pragma unroll
        for (int j = 0; j < 8; ++j) acc[i][j] = 0.f;

    float4 a4 = *reinterpret_cast<const float4*>(aptr);
    float4 b4 = *reinterpret_cast<const float4*>(bptr);

    for (int kt = 0; kt < 128; ++kt) {
        __syncthreads();
        As[half * 4 + 0][row] = a4.x;
        As[half * 4 + 1][row] = a4.y;
        As[half * 4 + 2][row] = a4.z;
        As[half * 4 + 3][row] = a4.w;
        Bs[half * 4 + 0][row] = b4.x;
        Bs[half * 4 + 1][row] = b4.y;
        Bs[half * 4 + 2][row] = b4.z;
        Bs[half * 4 + 3][row] = b4.w;
        __syncthreads();
        if (kt < 127) {
            a4 = *reinterpret_cast<const float4*>(aptr + (kt + 1) * 8);
            b4 = *reinterpret_cast<const float4*>(bptr + (kt + 1) * 8);
        }
#pragma unroll
        for (int kk = 0; kk < 8; ++kk) {
            float4 a0 = *reinterpret_cast<const float4*>(&As[kk][ty * 4]);
            float4 a1 = *reinterpret_cast<const float4*>(&As[kk][64 + ty * 4]);
            float4 b0 = *reinterpret_cast<const float4*>(&Bs[kk][tx * 4]);
            float4 b1 = *reinterpret_cast<const float4*>(&Bs[kk][64 + tx * 4]);
            float av[8] = {a0.x, a0.y, a0.z, a0.w, a1.x, a1.y, a1.z, a1.w};
            float bv[8] = {b0.x, b0.y, b0.z, b0.w, b1.x, b1.y, b1.z, b1.w};
#pragma unroll
            for (int i = 0; i < 8; ++i)
#pragma unroll
                for (int j = 0; j < 8; ++j)
                    acc[i][j] = fmaf(av[i], bv[j], acc[i][j]);
        }
    }

    float inv = 15.0f / mdm[0];
    float fs[8], es[8];
#pragma unroll
    for (int ig = 0; ig < 2; ++ig)
#pragma unroll
        for (int i = 0; i < 4; ++i)
            fs[ig * 4 + i] = fsq[bm * 128 + ig * 64 + ty * 4 + i];
#pragma unroll
    for (int jg = 0; jg < 2; ++jg)
#pragma unroll
        for (int j = 0; j < 4; ++j)
            es[jg * 4 + j] = esq[bn * 128 + jg * 64 + tx * 4 + j];

#pragma unroll
    for (int jg = 0; jg < 2; ++jg) {
#pragma unroll
        for (int j = 0; j < 4; ++j) {
            int k = bn * 128 + jg * 64 + tx * 4 + j;
#pragma unroll
            for (int ig = 0; ig < 2; ++ig) {
                int p0 = bm * 128 + ig * 64 + ty * 4;   // multiple of 4
                int b  = p0 / 144;
                int hw = p0 - b * 144;                  // run of 4 stays in b
                float4 v;
                v.x = inv * (2.f * acc[ig * 4 + 0][jg * 4 + j] - fs[ig * 4 + 0] - es[jg * 4 + j]);
                v.y = inv * (2.f * acc[ig * 4 + 1][jg * 4 + j] - fs[ig * 4 + 1] - es[jg * 4 + j]);
                v.z = inv * (2.f * acc[ig * 4 + 2][jg * 4 + j] - fs[ig * 4 + 2] - es[jg * 4 + j]);
                v.w = inv * (2.f * acc[ig * 4 + 3][jg * 4 + j] - fs[ig * 4 + 3] - es[jg * 4 + j]);
                *reinterpret_cast<float4*>(
                    &codes[(size_t)(b * 8192 + k) * 144 + hw]) = v;
            }
        }
    }
}

// ---------------------------------------------------------------------------
// 4) Partial max over k (8 splits of 1024), coalesced across hw
__global__ void pass_max(const float* __restrict__ codes,
                         float* __restrict__ pmax) {
    int ks = blockIdx.x, b = blockIdx.y;
    int t = threadIdx.x;
    if (t >= 144) return;
    const float* p = codes + ((size_t)b * 8192 + ks * 1024) * 144 + t;
    float m = -INFINITY;
#pragma unroll 8
    for (int kk = 0; kk < 1024; ++kk) m = fmaxf(m, p[(size_t)kk * 144]);
    pmax[(b * 8 + ks) * 144 + t] = m;
}

__global__ void comb_max(const float* __restrict__ pmax,
                         float* __restrict__ rmax) {
    int idx = blockIdx.x * 256 + threadIdx.x;
    if (idx >= MM) return;
    int b = idx / 144, hw = idx - b * 144;
    float m = -INFINITY;
#pragma unroll
    for (int ks = 0; ks < 8; ++ks) m = fmaxf(m, pmax[(b * 8 + ks) * 144 + hw]);
    rmax[idx] = m;
}

// ---------------------------------------------------------------------------
// 5) exp(logit - rowmax) writeback + partial sum
__global__ void pass_expsum(float* __restrict__ codes,
                            const float* __restrict__ rmax,
                            float* __restrict__ psum) {
    int ks = blockIdx.x, b = blockIdx.y;
    int t = threadIdx.x;
    if (t >= 144) return;
    float* p = codes + ((size_t)b * 8192 + ks * 1024) * 144 + t;
    float rm = rmax[b * 144 + t];
    float s = 0.f;
#pragma unroll 8
    for (int kk = 0; kk < 1024; ++kk) {
        float v = expf(p[(size_t)kk * 144] - rm);
        p[(size_t)kk * 144] = v;
        s += v;
    }
    psum[(b * 8 + ks) * 144 + t] = s;
}

__global__ void comb_sum(const float* __restrict__ psum,
                         float* __restrict__ rinv) {
    int idx = blockIdx.x * 256 + threadIdx.x;
    if (idx >= MM) return;
    int b = idx / 144, hw = idx - b * 144;
    float s = 0.f;
#pragma unroll
    for (int ks = 0; ks < 8; ++ks) s += psum[(b * 8 + ks) * 144 + hw];
    rinv[idx] = 1.f / s;
}

// ---------------------------------------------------------------------------
// 6) Scale codes by 1/sum and reduce per-(b,k) max over hw -> bow
__global__ void scale_bow(float* __restrict__ codes,
                          const float* __restrict__ rinv,
                          float* __restrict__ bow) {
    int wid = threadIdx.x >> 6, l = threadIdx.x & 63;
    int r = blockIdx.x * 4 + wid;        // (b*8192 + k)
    int b = r >> 13;
    float* p = codes + (size_t)r * 144;
    const float* ri = rinv + b * 144;
    float m = 0.f;
    for (int hw = l; hw < 144; hw += 64) {
        float v = p[hw] * ri[hw];
        p[hw] = v;
        m = fmaxf(m, v);
    }
#pragma unroll
    for (int off = 32; off; off >>= 1) m = fmaxf(m, __shfl_down(m, off));
    if (l == 0) bow[r] = m;
}

// ---------------------------------------------------------------------------
// 7) L1-normalize bow per b
__global__ void bow_norm(float* __restrict__ bow) {
    __shared__ float lds[4];
    __shared__ float stot;
    int b = blockIdx.x;
    float* p = bow + b * 8192;
    float s = 0.f;
    for (int i = threadIdx.x; i < 8192; i += 256) s += fabsf(p[i]);
#pragma unroll
    for (int off = 32; off; off >>= 1) s += __shfl_down(s, off);
    int wid = threadIdx.x >> 6, l = threadIdx.x & 63;
    if (l == 0) lds[wid] = s;
    __syncthreads();
    if (threadIdx.x == 0) stot = 1.f / (lds[0] + lds[1] + lds[2] + lds[3]);
    __syncthreads();
    float inv = stot;
    for (int i = threadIdx.x; i < 8192; i += 256) p[i] *= inv;
}

// ---------------------------------------------------------------------------
extern "C" void kernel_launch(void* const* d_in, const int* in_sizes, int n_in,
                              void* d_out, int out_size, void* d_ws, size_t ws_size,
                              hipStream_t stream) {
    const float* feat = (const float*)d_in[0];
    const float* emb  = (const float*)d_in[1];
    const float* mdm  = (const float*)d_in[2];
    float* bow   = (float*)d_out;
    float* codes = (float*)d_out + (size_t)BB * KK;   // 524288
    float* ws = (float*)d_ws;

    float* fT   = ws + OFF_FT;
    float* fsq  = ws + OFF_FSQ;
    float* esq  = ws + OFF_ESQ;
    float* pmax = ws + OFF_PMAX;
    float* rmax = ws + OFF_RMAX;
    float* psum = ws + OFF_PSUM;
    float* rinv = ws + OFF_RINV;

    crop_transpose<<<dim3(16, 64), 256, 0, stream>>>(feat, fT);
    rowsumsq<<<MM / 4, 256, 0, stream>>>(fT, fsq);
    rowsumsq<<<KK / 4, 256, 0, stream>>>(emb, esq);
    gemm_logits<<<dim3(64, 72), 256, 0, stream>>>(fT, emb, fsq, esq, mdm, codes);
    pass_max<<<dim3(8, 64), 192, 0, stream>>>(codes, pmax);
    comb_max<<<36, 256, 0, stream>>>(pmax, rmax);
    pass_expsum<<<dim3(8, 64), 192, 0, stream>>>(codes, rmax, psum);
    comb_sum<<<36, 256, 0, stream>>>(psum, rinv);
    scale_bow<<<(BB * KK) / 4, 256, 0, stream>>>(codes, rinv, bow);
    bow_norm<<<BB, 256, 0, stream>>>(bow);
}

// Round 2
// 954.194 us; speedup vs baseline: 2.4198x; 2.4198x over previous
//
#include <hip/hip_runtime.h>
#include <math.h>

#define BB   64
#define CC   1024
#define HWC  144
#define KK   8192
#define MM   9216
#define KCH  16          // online-softmax k chunks (512 k each)

typedef __attribute__((ext_vector_type(8))) short          bf16x8;
typedef __attribute__((ext_vector_type(8))) unsigned short u16x8;
typedef __attribute__((ext_vector_type(4))) float          f32x4;

// ws byte layout
#define FA_BYTES  ((size_t)MM * CC * 2 * 2)   // hi+lo bf16: 37,748,736
#define FB_BYTES  ((size_t)KK * CC * 2 * 2)   // 33,554,432
#define OFF_FA    0
#define OFF_FB    (OFF_FA + FA_BYTES)
#define OFF_ESQ   (OFF_FB + FB_BYTES)
#define OFF_PM    (OFF_ESQ + (size_t)KK * 4)
#define OFF_PS    (OFF_PM + (size_t)KCH * MM * 4)
#define OFF_RMAX  (OFF_PS + (size_t)KCH * MM * 4)
#define OFF_RINV  (OFF_RMAX + (size_t)MM * 4)

__device__ inline unsigned short f2bf(float x) {
    union { float f; unsigned u; } v; v.f = x;
    unsigned r = v.u + 0x7fffu + ((v.u >> 16) & 1u);
    return (unsigned short)(r >> 16);
}
__device__ inline float bf2f(unsigned short h) {
    union { unsigned u; float f; } v; v.u = (unsigned)h << 16;
    return v.f;
}

// ---------------------------------------------------------------------------
// Prep A: crop + transpose + bf16 hi/lo split into k-major tiled slots.
// fA[bm][kt][which][slot], slot = chunk*128 + row holds 8 bf16 of
// A[bm*128+row][kt*32 + chunk*8 .. +7].
__global__ void prep_A(const float* __restrict__ feat, u16x8* __restrict__ fA) {
    int gid = blockIdx.x * 256 + threadIdx.x;        // < 9216*128
    int p = gid >> 7, ch = gid & 127;
    int b = p / 144, hw = p - b * 144, h = hw / 12, w = hw - h * 12;
    int bm = p >> 7, row = p & 127;
    int kt = ch >> 2, chunk = ch & 3;
    const float* src = feat + (size_t)(b * 1024 + ch * 8) * 196
                       + (h + 1) * 14 + (w + 1);
    u16x8 hi, lo;
#pragma unroll
    for (int e = 0; e < 8; ++e) {
        float x = src[(size_t)e * 196];
        unsigned short h16 = f2bf(x);
        hi[e] = (short)h16;
        lo[e] = (short)f2bf(x - bf2f(h16));
    }
    size_t base = ((size_t)(bm * 32 + kt) * 2) * 512 + chunk * 128 + row;
    fA[base] = hi;
    fA[base + 512] = lo;
}

// Prep B: same tiling for embedding [8192][1024]
__global__ void prep_B(const float* __restrict__ emb, u16x8* __restrict__ fB) {
    int gid = blockIdx.x * 256 + threadIdx.x;        // < 8192*128
    int n = gid >> 7, ch = gid & 127;
    int bn = n >> 7, row = n & 127;
    int kt = ch >> 2, chunk = ch & 3;
    const float4* src = reinterpret_cast<const float4*>(emb + (size_t)n * 1024 + ch * 8);
    float4 v0 = src[0], v1 = src[1];
    float xs[8] = {v0.x, v0.y, v0.z, v0.w, v1.x, v1.y, v1.z, v1.w};
    u16x8 hi, lo;
#pragma unroll
    for (int e = 0; e < 8; ++e) {
        unsigned short h16 = f2bf(xs[e]);
        hi[e] = (short)h16;
        lo[e] = (short)f2bf(xs[e] - bf2f(h16));
    }
    size_t base = ((size_t)(bn * 32 + kt) * 2) * 512 + chunk * 128 + row;
    fB[base] = hi;
    fB[base + 512] = lo;
}

// Row sum-of-squares for embedding (fp32 exact)
__global__ void rowsumsq(const float* __restrict__ src, float* __restrict__ dst) {
    int row = blockIdx.x * 4 + (threadIdx.x >> 6);
    int l = threadIdx.x & 63;
    const float4* p = reinterpret_cast<const float4*>(src + (size_t)row * 1024);
    float s = 0.f;
#pragma unroll
    for (int it = 0; it < 4; ++it) {
        float4 v = p[l + it * 64];
        s += v.x * v.x + v.y * v.y + v.z * v.z + v.w * v.w;
    }
#pragma unroll
    for (int off = 32; off; off >>= 1) s += __shfl_down(s, off);
    if (l == 0) dst[row] = s;
}

// ---------------------------------------------------------------------------
// MFMA GEMM, bf16x3 split: logits[b][k][hw] = inv*(2*cross - esq[k])
// 128x128 tile, BK=32, 4 waves (2x2 of 64x64), double-buffered LDS.
__global__ __launch_bounds__(256, 2)
void gemm_mfma(const char* __restrict__ fA, const char* __restrict__ fB,
               const float* __restrict__ esq, const float* __restrict__ mdm,
               float* __restrict__ codes) {
    __shared__ __align__(16) char smem[65536];   // 2 x (Ahi|Alo|Bhi|Blo) x 8KB

    int flat = blockIdx.y * 64 + blockIdx.x;     // 4608 blocks, %8==0
    int swz = (flat & 7) * 576 + (flat >> 3);    // XCD-aware, bijective
    int bm = swz >> 6, bn = swz & 63;

    int tid = threadIdx.x;
    int l = tid & 63, lr = l & 15, lc = l >> 4;
    int wv = tid >> 6, wr = wv >> 1, wc = wv & 1;

    const char* gA = fA + (size_t)(bm * 32) * 16384;
    const char* gB = fB + (size_t)(bn * 32) * 16384;

    f32x4 acc[4][4];
#pragma unroll
    for (int i = 0; i < 4; ++i)
#pragma unroll
        for (int j = 0; j < 4; ++j) acc[i][j] = (f32x4){0.f, 0.f, 0.f, 0.f};

    auto stage = [&](int nb, int kt) {
        char* db = smem + nb * 32768;
        const char* ga = gA + (size_t)kt * 16384;
        const char* gb = gB + (size_t)kt * 16384;
#pragma unroll
        for (int i = 0; i < 4; ++i) {
            int off = (wv * 4 + i) * 1024;
            __builtin_amdgcn_global_load_lds(
                (const __attribute__((address_space(1))) void*)(ga + off + l * 16),
                (__attribute__((address_space(3))) void*)(db + off), 16, 0, 0);
            __builtin_amdgcn_global_load_lds(
                (const __attribute__((address_space(1))) void*)(gb + off + l * 16),
                (__attribute__((address_space(3))) void*)(db + 16384 + off), 16, 0, 0);
        }
    };

    stage(0, 0);
    __syncthreads();
    int cur = 0;
    for (int kt = 0; kt < 32; ++kt) {
        if (kt < 31) stage(cur ^ 1, kt + 1);
        const char* bufc = smem + cur * 32768;
        bf16x8 ahi[4], alo[4], bhi[4], blo[4];
#pragma unroll
        for (int f = 0; f < 4; ++f) {
            int ao = ((lc * 128) + wr * 64 + f * 16 + lr) * 16;
            ahi[f] = *(const bf16x8*)(bufc + ao);
            alo[f] = *(const bf16x8*)(bufc + 8192 + ao);
            int bo = ((lc * 128) + wc * 64 + f * 16 + lr) * 16;
            bhi[f] = *(const bf16x8*)(bufc + 16384 + bo);
            blo[f] = *(const bf16x8*)(bufc + 24576 + bo);
        }
#pragma unroll
        for (int fi = 0; fi < 4; ++fi)
#pragma unroll
            for (int fj = 0; fj < 4; ++fj) {
                acc[fi][fj] = __builtin_amdgcn_mfma_f32_16x16x32_bf16(
                    ahi[fi], bhi[fj], acc[fi][fj], 0, 0, 0);
                acc[fi][fj] = __builtin_amdgcn_mfma_f32_16x16x32_bf16(
                    ahi[fi], blo[fj], acc[fi][fj], 0, 0, 0);
                acc[fi][fj] = __builtin_amdgcn_mfma_f32_16x16x32_bf16(
                    alo[fi], bhi[fj], acc[fi][fj], 0, 0, 0);
            }
        __syncthreads();
        cur ^= 1;
    }

    float inv = 15.0f / mdm[0];
    float es[4];
#pragma unroll
    for (int fj = 0; fj < 4; ++fj)
        es[fj] = esq[bn * 128 + wc * 64 + fj * 16 + lr];

#pragma unroll
    for (int fi = 0; fi < 4; ++fi) {
        int p0 = bm * 128 + wr * 64 + fi * 16 + lc * 4;   // multiple of 4
        int b = p0 / 144, hw = p0 - b * 144;              // 4-run stays in b
#pragma unroll
        for (int fj = 0; fj < 4; ++fj) {
            int k = bn * 128 + wc * 64 + fj * 16 + lr;
            float4 v;
            v.x = inv * (2.f * acc[fi][fj].x - es[fj]);
            v.y = inv * (2.f * acc[fi][fj].y - es[fj]);
            v.z = inv * (2.f * acc[fi][fj].z - es[fj]);
            v.w = inv * (2.f * acc[fi][fj].w - es[fj]);
            *reinterpret_cast<float4*>(
                codes + ((size_t)(b * 8192 + k)) * 144 + hw) = v;
        }
    }
}

// ---------------------------------------------------------------------------
// Online max+sum over k (one read of logits)
__global__ void pass_online(const float* __restrict__ codes,
                            float* __restrict__ pm, float* __restrict__ ps) {
    int idx = blockIdx.x * 256 + threadIdx.x;   // KCH*9216, p fastest in block
    int c = idx / MM, p = idx - c * MM;
    int b = p / 144, hw = p - b * 144;
    const float* ptr = codes + ((size_t)b * 8192 + c * 512) * 144 + hw;
    float m = -INFINITY, s = 0.f;
#pragma unroll 8
    for (int kk = 0; kk < 512; ++kk) {
        float v = ptr[(size_t)kk * 144];
        if (v > m) { s = s * __expf(m - v) + 1.f; m = v; }
        else       { s += __expf(v - m); }
    }
    pm[idx] = m;
    ps[idx] = s;
}

__global__ void comb_online(const float* __restrict__ pm, const float* __restrict__ ps,
                            float* __restrict__ rmax, float* __restrict__ rinv) {
    int p = blockIdx.x * 256 + threadIdx.x;     // 9216 = 36*256
    float gm = -INFINITY;
#pragma unroll
    for (int c = 0; c < KCH; ++c) gm = fmaxf(gm, pm[c * MM + p]);
    float s = 0.f;
#pragma unroll
    for (int c = 0; c < KCH; ++c) s += ps[c * MM + p] * __expf(pm[c * MM + p] - gm);
    rmax[p] = gm;
    rinv[p] = 1.f / s;
}

// ---------------------------------------------------------------------------
// exp + scale + write + per-(b,k) max over hw -> bow
__global__ void scale_bow(float* __restrict__ codes,
                          const float* __restrict__ rmax,
                          const float* __restrict__ rinv,
                          float* __restrict__ bow) {
    int wid = threadIdx.x >> 6, lane = threadIdx.x & 63;
    int r = blockIdx.x * 4 + wid;        // b*8192 + k
    int b = r >> 13;
    float* p = codes + (size_t)r * 144;
    const float* rm = rmax + b * 144;
    const float* ri = rinv + b * 144;
    float m = 0.f;
    for (int hw = lane; hw < 144; hw += 64) {
        float v = __expf(p[hw] - rm[hw]) * ri[hw];
        p[hw] = v;
        m = fmaxf(m, v);
    }
#pragma unroll
    for (int off = 32; off; off >>= 1) m = fmaxf(m, __shfl_down(m, off));
    if (lane == 0) bow[r] = m;
}

// L1-normalize bow per b
__global__ void bow_norm(float* __restrict__ bow) {
    __shared__ float lds[4];
    __shared__ float stot;
    int b = blockIdx.x;
    float* p = bow + b * 8192;
    float s = 0.f;
    for (int i = threadIdx.x; i < 8192; i += 256) s += fabsf(p[i]);
#pragma unroll
    for (int off = 32; off; off >>= 1) s += __shfl_down(s, off);
    int wid = threadIdx.x >> 6, l = threadIdx.x & 63;
    if (l == 0) lds[wid] = s;
    __syncthreads();
    if (threadIdx.x == 0) stot = 1.f / (lds[0] + lds[1] + lds[2] + lds[3]);
    __syncthreads();
    float inv = stot;
    for (int i = threadIdx.x; i < 8192; i += 256) p[i] *= inv;
}

// ---------------------------------------------------------------------------
extern "C" void kernel_launch(void* const* d_in, const int* in_sizes, int n_in,
                              void* d_out, int out_size, void* d_ws, size_t ws_size,
                              hipStream_t stream) {
    const float* feat = (const float*)d_in[0];
    const float* emb  = (const float*)d_in[1];
    const float* mdm  = (const float*)d_in[2];
    float* bow   = (float*)d_out;
    float* codes = (float*)d_out + (size_t)BB * KK;

    char* ws = (char*)d_ws;
    u16x8* fA   = (u16x8*)(ws + OFF_FA);
    u16x8* fB   = (u16x8*)(ws + OFF_FB);
    float* esq  = (float*)(ws + OFF_ESQ);
    float* pm   = (float*)(ws + OFF_PM);
    float* ps   = (float*)(ws + OFF_PS);
    float* rmax = (float*)(ws + OFF_RMAX);
    float* rinv = (float*)(ws + OFF_RINV);

    prep_A<<<4608, 256, 0, stream>>>(feat, fA);
    prep_B<<<4096, 256, 0, stream>>>(emb, fB);
    rowsumsq<<<KK / 4, 256, 0, stream>>>(emb, esq);
    gemm_mfma<<<dim3(64, 72), 256, 0, stream>>>((const char*)fA, (const char*)fB,
                                                esq, mdm, codes);
    pass_online<<<KCH * MM / 256, 256, 0, stream>>>(codes, pm, ps);
    comb_online<<<36, 256, 0, stream>>>(pm, ps, rmax, rinv);
    scale_bow<<<(BB * KK) / 4, 256, 0, stream>>>(codes, rmax, rinv, bow);
    bow_norm<<<BB, 256, 0, stream>>>(bow);
}

// Round 3
// 578.996 us; speedup vs baseline: 3.9879x; 1.6480x over previous
//
#include <hip/hip_runtime.h>
#include <math.h>

#define BB   64
#define CC   1024
#define HWC  144
#define KK   8192
#define MM   9216
#define NBN  64          // number of 128-code blocks

typedef __attribute__((ext_vector_type(8))) short          bf16x8;
typedef __attribute__((ext_vector_type(8))) unsigned short u16x8;
typedef __attribute__((ext_vector_type(4))) float          f32x4;

// ws byte layout
#define FA_BYTES  ((size_t)MM * CC * 2 * 2)   // hi+lo bf16
#define FB_BYTES  ((size_t)KK * CC * 2 * 2)
#define OFF_FA    0
#define OFF_FB    (OFF_FA + FA_BYTES)
#define OFF_ESQ   (OFF_FB + FB_BYTES)
#define OFF_PM    (OFF_ESQ + (size_t)KK * 4)
#define OFF_PS    (OFF_PM + (size_t)NBN * MM * 4)
#define OFF_FACT  (OFF_PS + (size_t)NBN * MM * 4)

__device__ inline unsigned short f2bf(float x) {
    union { float f; unsigned u; } v; v.f = x;
    unsigned r = v.u + 0x7fffu + ((v.u >> 16) & 1u);
    return (unsigned short)(r >> 16);
}
__device__ inline float bf2f(unsigned short h) {
    union { unsigned u; float f; } v; v.u = (unsigned)h << 16;
    return v.f;
}

// ---------------------------------------------------------------------------
// Prep A: crop + transpose + bf16 hi/lo split, LDS-tiled, coalesced writes.
__global__ __launch_bounds__(256)
void prep_A(const float* __restrict__ feat, u16x8* __restrict__ fA) {
    __shared__ float tile[64][145];
    int cb = blockIdx.x;      // 16 channel blocks of 64
    int b  = blockIdx.y;
    for (int idx = threadIdx.x; idx < 64 * 144; idx += 256) {
        int r = idx / 144, hw = idx - r * 144;
        int h = hw / 12, w = hw - h * 12;
        tile[r][hw] = feat[(size_t)((b * 1024 + cb * 64 + r) * 196)
                           + (h + 1) * 14 + (w + 1)];
    }
    __syncthreads();
    for (int idx = threadIdx.x; idx < 8 * 144; idx += 256) {
        int g = idx / 144, hw = idx - g * 144;       // hw fastest -> coalesced
        int p = b * 144 + hw;
        int bm = p >> 7, row = p & 127;
        int cg = cb * 64 + g * 8;                    // first channel of group
        int kt = cg >> 5, chunk = (cg >> 3) & 3;
        u16x8 hi, lo;
#pragma unroll
        for (int e = 0; e < 8; ++e) {
            float x = tile[g * 8 + e][hw];
            unsigned short h16 = f2bf(x);
            hi[e] = (short)h16;
            lo[e] = (short)f2bf(x - bf2f(h16));
        }
        size_t base = ((size_t)(bm * 32 + kt) * 2) * 512 + chunk * 128 + row;
        fA[base] = hi;
        fA[base + 512] = lo;
    }
}

// Prep B: LDS-tiled transpose of embedding, coalesced both sides.
__global__ __launch_bounds__(256)
void prep_B(const float* __restrict__ emb, u16x8* __restrict__ fB) {
    __shared__ float tile[128][65];
    int cb = blockIdx.x;      // 16 channel blocks of 64
    int bn = blockIdx.y;      // 64 n blocks of 128
#pragma unroll
    for (int i = 0; i < 8; ++i) {
        int idx = threadIdx.x + i * 256;             // < 2048
        int nl = idx >> 4, c4 = idx & 15;
        const float4 v = *reinterpret_cast<const float4*>(
            emb + (size_t)(bn * 128 + nl) * 1024 + cb * 64 + c4 * 4);
        tile[nl][c4 * 4 + 0] = v.x;
        tile[nl][c4 * 4 + 1] = v.y;
        tile[nl][c4 * 4 + 2] = v.z;
        tile[nl][c4 * 4 + 3] = v.w;
    }
    __syncthreads();
#pragma unroll
    for (int i = 0; i < 4; ++i) {
        int idx = threadIdx.x + i * 256;             // < 1024
        int kc = idx >> 7, row = idx & 127;          // row fastest -> coalesced
        int ktl = kc >> 2, chunk = kc & 3;
        int cl = ktl * 32 + chunk * 8;
        u16x8 hi, lo;
#pragma unroll
        for (int e = 0; e < 8; ++e) {
            float x = tile[row][cl + e];
            unsigned short h16 = f2bf(x);
            hi[e] = (short)h16;
            lo[e] = (short)f2bf(x - bf2f(h16));
        }
        int kt = cb * 2 + ktl;
        size_t base = ((size_t)(bn * 32 + kt) * 2) * 512 + chunk * 128 + row;
        fB[base] = hi;
        fB[base + 512] = lo;
    }
}

// Row sum-of-squares for embedding (fp32 exact)
__global__ void rowsumsq(const float* __restrict__ src, float* __restrict__ dst) {
    int row = blockIdx.x * 4 + (threadIdx.x >> 6);
    int l = threadIdx.x & 63;
    const float4* p = reinterpret_cast<const float4*>(src + (size_t)row * 1024);
    float s = 0.f;
#pragma unroll
    for (int it = 0; it < 4; ++it) {
        float4 v = p[l + it * 64];
        s += v.x * v.x + v.y * v.y + v.z * v.z + v.w * v.w;
    }
#pragma unroll
    for (int off = 32; off; off >>= 1) s += __shfl_down(s, off);
    if (l == 0) dst[row] = s;
}

// ---------------------------------------------------------------------------
// MFMA GEMM + fused partial softmax epilogue.
// Writes E = exp2(l2 - m_part) (NT) and per-(bn, pixel) pm/ps partials.
__global__ __launch_bounds__(256, 2)
void gemm_mfma(const char* __restrict__ fA, const char* __restrict__ fB,
               const float* __restrict__ esq, const float* __restrict__ mdm,
               float* __restrict__ codes, float* __restrict__ pm,
               float* __restrict__ ps) {
    __shared__ __align__(16) char smem[65536];

    int flat = blockIdx.y * 64 + blockIdx.x;
    int swz = (flat & 7) * 576 + (flat >> 3);    // XCD-aware, bijective
    int bm = swz >> 6, bn = swz & 63;

    int tid = threadIdx.x;
    int l = tid & 63, lr = l & 15, lc = l >> 4;
    int wv = tid >> 6, wr = wv >> 1, wc = wv & 1;

    const char* gA = fA + (size_t)(bm * 32) * 16384;
    const char* gB = fB + (size_t)(bn * 32) * 16384;

    f32x4 acc[4][4];
#pragma unroll
    for (int i = 0; i < 4; ++i)
#pragma unroll
        for (int j = 0; j < 4; ++j) acc[i][j] = (f32x4){0.f, 0.f, 0.f, 0.f};

    auto stage = [&](int nb, int kt) {
        char* db = smem + nb * 32768;
        const char* ga = gA + (size_t)kt * 16384;
        const char* gb = gB + (size_t)kt * 16384;
#pragma unroll
        for (int i = 0; i < 4; ++i) {
            int off = (wv * 4 + i) * 1024;
            __builtin_amdgcn_global_load_lds(
                (const __attribute__((address_space(1))) void*)(ga + off + l * 16),
                (__attribute__((address_space(3))) void*)(db + off), 16, 0, 0);
            __builtin_amdgcn_global_load_lds(
                (const __attribute__((address_space(1))) void*)(gb + off + l * 16),
                (__attribute__((address_space(3))) void*)(db + 16384 + off), 16, 0, 0);
        }
    };

    stage(0, 0);
    __syncthreads();
    int cur = 0;
    for (int kt = 0; kt < 32; ++kt) {
        if (kt < 31) stage(cur ^ 1, kt + 1);
        const char* bufc = smem + cur * 32768;
        bf16x8 ahi[4], alo[4], bhi[4], blo[4];
#pragma unroll
        for (int f = 0; f < 4; ++f) {
            int ao = ((lc * 128) + wr * 64 + f * 16 + lr) * 16;
            ahi[f] = *(const bf16x8*)(bufc + ao);
            alo[f] = *(const bf16x8*)(bufc + 8192 + ao);
            int bo = ((lc * 128) + wc * 64 + f * 16 + lr) * 16;
            bhi[f] = *(const bf16x8*)(bufc + 16384 + bo);
            blo[f] = *(const bf16x8*)(bufc + 24576 + bo);
        }
#pragma unroll
        for (int fi = 0; fi < 4; ++fi)
#pragma unroll
            for (int fj = 0; fj < 4; ++fj) {
                acc[fi][fj] = __builtin_amdgcn_mfma_f32_16x16x32_bf16(
                    ahi[fi], bhi[fj], acc[fi][fj], 0, 0, 0);
                acc[fi][fj] = __builtin_amdgcn_mfma_f32_16x16x32_bf16(
                    ahi[fi], blo[fj], acc[fi][fj], 0, 0, 0);
                acc[fi][fj] = __builtin_amdgcn_mfma_f32_16x16x32_bf16(
                    alo[fi], bhi[fj], acc[fi][fj], 0, 0, 0);
            }
        __syncthreads();
        cur ^= 1;
    }

    // ---- fused partial-softmax epilogue (base-2 domain) ----
    float invl2 = (15.0f / mdm[0]) * 1.44269504089f;
    float s2 = 2.0f * invl2;
    float e2[4];
#pragma unroll
    for (int fj = 0; fj < 4; ++fj)
        e2[fj] = invl2 * esq[bn * 128 + wc * 64 + fj * 16 + lr];

    // acc -> l2 logits
#pragma unroll
    for (int fi = 0; fi < 4; ++fi)
#pragma unroll
        for (int fj = 0; fj < 4; ++fj)
#pragma unroll
            for (int j = 0; j < 4; ++j)
                acc[fi][fj][j] = s2 * acc[fi][fj][j] - e2[fj];

    // per-(fi,j) max over this wave's 64 codes
    float mx[4][4];
#pragma unroll
    for (int fi = 0; fi < 4; ++fi)
#pragma unroll
        for (int j = 0; j < 4; ++j) {
            float m = acc[fi][0][j];
            m = fmaxf(m, acc[fi][1][j]);
            m = fmaxf(m, acc[fi][2][j]);
            m = fmaxf(m, acc[fi][3][j]);
            mx[fi][j] = m;
        }
#pragma unroll
    for (int off = 1; off < 16; off <<= 1)
#pragma unroll
        for (int fi = 0; fi < 4; ++fi)
#pragma unroll
            for (int j = 0; j < 4; ++j)
                mx[fi][j] = fmaxf(mx[fi][j], __shfl_xor(mx[fi][j], off));

    float* sm = (float*)smem;     // [0..255]: max[wc][128]; [256..511]: sum
    if (lr == 0) {
#pragma unroll
        for (int fi = 0; fi < 4; ++fi)
#pragma unroll
            for (int j = 0; j < 4; ++j)
                sm[wc * 128 + wr * 64 + fi * 16 + lc * 4 + j] = mx[fi][j];
    }
    __syncthreads();
    float mp[4][4];
#pragma unroll
    for (int fi = 0; fi < 4; ++fi)
#pragma unroll
        for (int j = 0; j < 4; ++j) {
            int pi = wr * 64 + fi * 16 + lc * 4 + j;
            mp[fi][j] = fmaxf(sm[pi], sm[128 + pi]);
        }

    float ss[4][4];
#pragma unroll
    for (int fi = 0; fi < 4; ++fi)
#pragma unroll
        for (int j = 0; j < 4; ++j) ss[fi][j] = 0.f;
#pragma unroll
    for (int fi = 0; fi < 4; ++fi)
#pragma unroll
        for (int fj = 0; fj < 4; ++fj)
#pragma unroll
            for (int j = 0; j < 4; ++j) {
                float E = exp2f(acc[fi][fj][j] - mp[fi][j]);
                acc[fi][fj][j] = E;
                ss[fi][j] += E;
            }
#pragma unroll
    for (int off = 1; off < 16; off <<= 1)
#pragma unroll
        for (int fi = 0; fi < 4; ++fi)
#pragma unroll
            for (int j = 0; j < 4; ++j)
                ss[fi][j] += __shfl_xor(ss[fi][j], off);
    if (lr == 0) {
#pragma unroll
        for (int fi = 0; fi < 4; ++fi)
#pragma unroll
            for (int j = 0; j < 4; ++j)
                sm[256 + wc * 128 + wr * 64 + fi * 16 + lc * 4 + j] = ss[fi][j];
    }
    __syncthreads();
    if (tid < 128) {
        int p = bm * 128 + tid;
        pm[(size_t)bn * MM + p] = fmaxf(sm[tid], sm[128 + tid]);
        ps[(size_t)bn * MM + p] = sm[256 + tid] + sm[384 + tid];
    }

    // NT-store E
#pragma unroll
    for (int fi = 0; fi < 4; ++fi) {
        int p0 = bm * 128 + wr * 64 + fi * 16 + lc * 4;
        int b = p0 / 144, hw = p0 - b * 144;
#pragma unroll
        for (int fj = 0; fj < 4; ++fj) {
            int k = bn * 128 + wc * 64 + fj * 16 + lr;
            __builtin_nontemporal_store(
                acc[fi][fj],
                (f32x4*)(codes + ((size_t)(b * 8192 + k)) * 144 + hw));
        }
    }
}

// ---------------------------------------------------------------------------
// Combine partials: factor[bn][p] = 2^(pm - m_glob) / S
__global__ void comb_factor(const float* __restrict__ pm,
                            const float* __restrict__ ps,
                            float* __restrict__ factor) {
    int p = blockIdx.x * 256 + threadIdx.x;      // 9216 = 36*256
    float m = -INFINITY;
#pragma unroll 8
    for (int bn = 0; bn < NBN; ++bn) m = fmaxf(m, pm[(size_t)bn * MM + p]);
    float S = 0.f;
#pragma unroll 8
    for (int bn = 0; bn < NBN; ++bn)
        S += ps[(size_t)bn * MM + p] * exp2f(pm[(size_t)bn * MM + p] - m);
    float is = 1.f / S;
#pragma unroll 8
    for (int bn = 0; bn < NBN; ++bn)
        factor[(size_t)bn * MM + p] = exp2f(pm[(size_t)bn * MM + p] - m) * is;
}

// ---------------------------------------------------------------------------
// codes = E * factor (in place), bow[r] = max over hw. One wave per row.
__global__ __launch_bounds__(256)
void scale_bow(float* __restrict__ codes, const float* __restrict__ factor,
               float* __restrict__ bow) {
    int wid = threadIdx.x >> 6, l = threadIdx.x & 63;
    int r = blockIdx.x * 4 + wid;                // b*8192 + k
    int b = r >> 13, k = r & 8191;
    f32x4* Cp = (f32x4*)(codes + (size_t)r * 144);
    const f32x4* Fp = (const f32x4*)(factor + (size_t)(k >> 7) * MM + b * 144);
    float m = 0.f;
    if (l < 36) {
        f32x4 e = __builtin_nontemporal_load(Cp + l);
        f32x4 f = Fp[l];
        f32x4 v = e * f;
        __builtin_nontemporal_store(v, Cp + l);
        m = fmaxf(fmaxf(v.x, v.y), fmaxf(v.z, v.w));
    }
#pragma unroll
    for (int off = 32; off; off >>= 1) m = fmaxf(m, __shfl_down(m, off));
    if (l == 0) bow[r] = m;
}

// L1-normalize bow per b
__global__ void bow_norm(float* __restrict__ bow) {
    __shared__ float lds[4];
    __shared__ float stot;
    int b = blockIdx.x;
    float* p = bow + b * 8192;
    float s = 0.f;
    for (int i = threadIdx.x; i < 8192; i += 256) s += fabsf(p[i]);
#pragma unroll
    for (int off = 32; off; off >>= 1) s += __shfl_down(s, off);
    int wid = threadIdx.x >> 6, l = threadIdx.x & 63;
    if (l == 0) lds[wid] = s;
    __syncthreads();
    if (threadIdx.x == 0) stot = 1.f / (lds[0] + lds[1] + lds[2] + lds[3]);
    __syncthreads();
    float inv = stot;
    for (int i = threadIdx.x; i < 8192; i += 256) p[i] *= inv;
}

// ---------------------------------------------------------------------------
extern "C" void kernel_launch(void* const* d_in, const int* in_sizes, int n_in,
                              void* d_out, int out_size, void* d_ws, size_t ws_size,
                              hipStream_t stream) {
    const float* feat = (const float*)d_in[0];
    const float* emb  = (const float*)d_in[1];
    const float* mdm  = (const float*)d_in[2];
    float* bow   = (float*)d_out;
    float* codes = (float*)d_out + (size_t)BB * KK;

    char* ws = (char*)d_ws;
    u16x8* fA    = (u16x8*)(ws + OFF_FA);
    u16x8* fB    = (u16x8*)(ws + OFF_FB);
    float* esq   = (float*)(ws + OFF_ESQ);
    float* pm    = (float*)(ws + OFF_PM);
    float* ps    = (float*)(ws + OFF_PS);
    float* fact  = (float*)(ws + OFF_FACT);

    prep_A<<<dim3(16, 64), 256, 0, stream>>>(feat, fA);
    prep_B<<<dim3(16, 64), 256, 0, stream>>>(emb, fB);
    rowsumsq<<<KK / 4, 256, 0, stream>>>(emb, esq);
    gemm_mfma<<<dim3(64, 72), 256, 0, stream>>>((const char*)fA, (const char*)fB,
                                                esq, mdm, codes, pm, ps);
    comb_factor<<<36, 256, 0, stream>>>(pm, ps, fact);
    scale_bow<<<(BB * KK) / 4, 256, 0, stream>>>(codes, fact, bow);
    bow_norm<<<BB, 256, 0, stream>>>(bow);
}